// Round 7
// baseline (570.759 us; speedup 1.0000x reference)
//
#include <hip/hip_runtime.h>
#include <hip/hip_bf16.h>

typedef short bf16x8 __attribute__((ext_vector_type(8)));
typedef float f32x4 __attribute__((ext_vector_type(4)));
using bf16 = __hip_bfloat16;

#define MFMA16(a, b, c) __builtin_amdgcn_mfma_f32_16x16x32_bf16(a, b, c, 0, 0, 0)

__device__ __forceinline__ float bf2f(unsigned short u) {
    return __uint_as_float(((unsigned)u) << 16);
}
__device__ __forceinline__ short f2b(float f) {
    __hip_bfloat16 h = __float2bfloat16(f);  // RNE
    return *reinterpret_cast<short*>(&h);
}

// B=4, N=2048, E=1024, H=16, D=64.  Contract: fp32 in, fp32 out, thr = 2% of max|ref|.
// GEMM (bt form): C[M,Nc] = A[M,K] * W[Nc,K]^T
// MODE 2: bf16 scatter into qkv ws. Q [bh][n][d] (pre-scaled 0.125), K [bh][n][d],
//         V TRANSPOSED [bh][d][n] so attention PV B-frags are contiguous in global.
// MODE 1: FP32 row-major [M,1024].
template <int MODE, int K, bool AF32, bool WF32>
__global__ __launch_bounds__(256) void gemm_bt_kernel(const void* __restrict__ Ap,
                                                      const void* __restrict__ Wp,
                                                      void* __restrict__ outp) {
    __shared__ bf16 As[64][72];
    __shared__ bf16 Ws[64][72];
    const int tid = threadIdx.x;
    const int lane = tid & 63;
    const int w = tid >> 6;
    const int wr = w >> 1, wc = w & 1;
    const int lm = lane & 15, kh = lane >> 4;
    const int m0 = blockIdx.y * 64, n0 = blockIdx.x * 64;
    const int srow = tid >> 2, scol = (tid & 3) * 16;

    f32x4 acc[2][2] = {};

    for (int k0 = 0; k0 < K; k0 += 64) {
        bf16x8 alo, ahi, wlo, whi;
        if (AF32) {
            const float* Arow = (const float*)Ap + (size_t)(m0 + srow) * K + k0 + scol;
            float4 v0 = *(const float4*)(Arow + 0);
            float4 v1 = *(const float4*)(Arow + 4);
            float4 v2 = *(const float4*)(Arow + 8);
            float4 v3 = *(const float4*)(Arow + 12);
            alo[0] = f2b(v0.x); alo[1] = f2b(v0.y); alo[2] = f2b(v0.z); alo[3] = f2b(v0.w);
            alo[4] = f2b(v1.x); alo[5] = f2b(v1.y); alo[6] = f2b(v1.z); alo[7] = f2b(v1.w);
            ahi[0] = f2b(v2.x); ahi[1] = f2b(v2.y); ahi[2] = f2b(v2.z); ahi[3] = f2b(v2.w);
            ahi[4] = f2b(v3.x); ahi[5] = f2b(v3.y); ahi[6] = f2b(v3.z); ahi[7] = f2b(v3.w);
        } else {
            const bf16* Arow = (const bf16*)Ap + (size_t)(m0 + srow) * K + k0 + scol;
            alo = *(const bf16x8*)(Arow + 0);
            ahi = *(const bf16x8*)(Arow + 8);
        }
        if (WF32) {
            const float* Wrow = (const float*)Wp + (size_t)(n0 + srow) * K + k0 + scol;
            float4 v0 = *(const float4*)(Wrow + 0);
            float4 v1 = *(const float4*)(Wrow + 4);
            float4 v2 = *(const float4*)(Wrow + 8);
            float4 v3 = *(const float4*)(Wrow + 12);
            wlo[0] = f2b(v0.x); wlo[1] = f2b(v0.y); wlo[2] = f2b(v0.z); wlo[3] = f2b(v0.w);
            wlo[4] = f2b(v1.x); wlo[5] = f2b(v1.y); wlo[6] = f2b(v1.z); wlo[7] = f2b(v1.w);
            whi[0] = f2b(v2.x); whi[1] = f2b(v2.y); whi[2] = f2b(v2.z); whi[3] = f2b(v2.w);
            whi[4] = f2b(v3.x); whi[5] = f2b(v3.y); whi[6] = f2b(v3.z); whi[7] = f2b(v3.w);
        } else {
            const bf16* Wrow = (const bf16*)Wp + (size_t)(n0 + srow) * K + k0 + scol;
            wlo = *(const bf16x8*)(Wrow + 0);
            whi = *(const bf16x8*)(Wrow + 8);
        }
        __syncthreads();
        *(bf16x8*)&As[srow][scol] = alo;
        *(bf16x8*)&As[srow][scol + 8] = ahi;
        *(bf16x8*)&Ws[srow][scol] = wlo;
        *(bf16x8*)&Ws[srow][scol + 8] = whi;
        __syncthreads();
#pragma unroll
        for (int ks = 0; ks < 2; ks++) {
            bf16x8 af0 = *(const bf16x8*)&As[wr * 32 + lm][ks * 32 + kh * 8];
            bf16x8 af1 = *(const bf16x8*)&As[wr * 32 + 16 + lm][ks * 32 + kh * 8];
            bf16x8 bf0 = *(const bf16x8*)&Ws[wc * 32 + lm][ks * 32 + kh * 8];
            bf16x8 bf1 = *(const bf16x8*)&Ws[wc * 32 + 16 + lm][ks * 32 + kh * 8];
            acc[0][0] = MFMA16(af0, bf0, acc[0][0]);
            acc[0][1] = MFMA16(af0, bf1, acc[0][1]);
            acc[1][0] = MFMA16(af1, bf0, acc[1][0]);
            acc[1][1] = MFMA16(af1, bf1, acc[1][1]);
        }
    }

#pragma unroll
    for (int mt = 0; mt < 2; mt++)
#pragma unroll
        for (int nt = 0; nt < 2; nt++) {
            f32x4 v = acc[mt][nt];
            const int gr0 = m0 + wr * 32 + mt * 16 + kh * 4;
            const int gc = n0 + wc * 32 + nt * 16 + lm;
            if (MODE == 2) {
                bf16* qkv = (bf16*)outp;
                const int which = gc >> 10;  // 0=q 1=k 2=v
                const int h = (gc >> 6) & 15;
                const int d = gc & 63;
                const int b = gr0 >> 11, n = gr0 & 2047;  // 4 rows share b (gr0 % 4 == 0)
                if (which == 2) {
                    // V transposed [bh][d][key]: 4 consecutive n -> one 8B store
                    short4 pk;
                    pk.x = f2b(v[0]); pk.y = f2b(v[1]); pk.z = f2b(v[2]); pk.w = f2b(v[3]);
                    *(short4*)&qkv[2ull * 8388608 +
                                   ((size_t)((b * 16 + h) * 64 + d)) * 2048 + n] = pk;
                } else {
#pragma unroll
                    for (int r = 0; r < 4; r++) {
                        float val = v[r];
                        if (which == 0) val *= 0.125f;  // fold D^-0.5 into Q (exact pow2)
                        qkv[(size_t)which * 8388608 +
                            ((size_t)((b * 16 + h) * 2048 + n + r)) * 64 + d] =
                            __float2bfloat16(val);
                    }
                }
            } else {
                float* o = (float*)outp;
#pragma unroll
                for (int r = 0; r < 4; r++) o[(size_t)(gr0 + r) * 1024 + gc] = v[r];
            }
        }
}

// MFMA flash attention v3: NO LDS for K/V, NO barriers. K/V fragments load directly
// from global (V pre-transposed to [bh][d][key] by the gemm). LDS only for the
// wave-private P C-layout -> A-layout round-trip. Block = 4 waves x 32 q-rows = 128 q.
// grid (N/128, B*H) = (16, 64).
__global__ __launch_bounds__(256) void attn_mfma_kernel(const unsigned short* __restrict__ Qg,
                                                        const unsigned short* __restrict__ Kg,
                                                        const unsigned short* __restrict__ Vtg,
                                                        unsigned short* __restrict__ O) {
    __shared__ short Ps[128][72];
    const int tid = threadIdx.x;
    const int lane = tid & 63;
    const int w = tid >> 6;
    const int lm = lane & 15;
    const int quad = lane >> 4;
    const int bh = blockIdx.y;
    const int n0 = blockIdx.x * 128;
    const size_t base = (size_t)bh * (2048 * 64);  // same element count for Kg and Vtg slices

    // Q fragments (A-layout), pre-scaled by 0.125 in the gemm; resident all 32 tiles
    bf16x8 qf[2][2];
#pragma unroll
    for (int mt = 0; mt < 2; mt++)
#pragma unroll
        for (int ks = 0; ks < 2; ks++)
            qf[mt][ks] = *(const bf16x8*)&Qg[base +
                                            (size_t)(n0 + w * 32 + mt * 16 + lm) * 64 +
                                            ks * 32 + quad * 8];

    f32x4 accO[2][4] = {};
    float mrow[2][4], lrow[2][4];
#pragma unroll
    for (int mt = 0; mt < 2; mt++)
#pragma unroll
        for (int r = 0; r < 4; r++) {
            mrow[mt][r] = -1e30f;
            lrow[mt][r] = 0.f;
        }

    for (int t = 0; t < 32; t++) {
        const int k0 = t * 64;

        // K fragments straight from global: B[n=key][k=d], contiguous 16B per lane
        bf16x8 kb[4][2];
#pragma unroll
        for (int nt = 0; nt < 4; nt++)
#pragma unroll
            for (int ks = 0; ks < 2; ks++)
                kb[nt][ks] = *(const bf16x8*)&Kg[base + (size_t)(k0 + nt * 16 + lm) * 64 +
                                                ks * 32 + quad * 8];

        f32x4 s[2][4];
#pragma unroll
        for (int mt = 0; mt < 2; mt++)
#pragma unroll
            for (int nt = 0; nt < 4; nt++) {
                f32x4 z = {};
                z = MFMA16(qf[mt][0], kb[nt][0], z);
                s[mt][nt] = MFMA16(qf[mt][1], kb[nt][1], z);
            }

        // Issue V fragment loads NOW; ~300 cyc of softmax VALU below hides their latency.
        // B[n=d][k=key] = Vtg[d][key], contiguous 16B per lane.
        bf16x8 vb[4][2];
#pragma unroll
        for (int nt = 0; nt < 4; nt++)
#pragma unroll
            for (int ks = 0; ks < 2; ks++)
                vb[nt][ks] = *(const bf16x8*)&Vtg[base + (size_t)(nt * 16 + lm) * 2048 +
                                                 k0 + ks * 32 + quad * 8];

        // online softmax (C-layout: row = quad*4+r, col = nt*16+lm)
#pragma unroll
        for (int mt = 0; mt < 2; mt++) {
            float mx[4];
#pragma unroll
            for (int r = 0; r < 4; r++)
                mx[r] = fmaxf(fmaxf(s[mt][0][r], s[mt][1][r]),
                              fmaxf(s[mt][2][r], s[mt][3][r]));
#pragma unroll
            for (int off = 1; off < 16; off <<= 1)
#pragma unroll
                for (int r = 0; r < 4; r++) mx[r] = fmaxf(mx[r], __shfl_xor(mx[r], off));
            float al[4];
#pragma unroll
            for (int r = 0; r < 4; r++) {
                const float mn = fmaxf(mrow[mt][r], mx[r]);
                al[r] = __expf(mrow[mt][r] - mn);
                mrow[mt][r] = mn;
            }
            float psum[4] = {0.f, 0.f, 0.f, 0.f};
#pragma unroll
            for (int nt = 0; nt < 4; nt++)
#pragma unroll
                for (int r = 0; r < 4; r++) {
                    const float p = __expf(s[mt][nt][r] - mrow[mt][r]);
                    psum[r] += p;
                    Ps[w * 32 + mt * 16 + quad * 4 + r][nt * 16 + lm] = f2b(p);
                }
#pragma unroll
            for (int off = 1; off < 16; off <<= 1)
#pragma unroll
                for (int r = 0; r < 4; r++) psum[r] += __shfl_xor(psum[r], off);
#pragma unroll
            for (int r = 0; r < 4; r++) lrow[mt][r] = lrow[mt][r] * al[r] + psum[r];
#pragma unroll
            for (int nt = 0; nt < 4; nt++)
#pragma unroll
                for (int r = 0; r < 4; r++) accO[mt][nt][r] *= al[r];
        }

        // PV: A-frags from wave-private Ps rows (same-wave RAW, lgkmcnt-ordered, no barrier)
        bf16x8 pa[2][2];
#pragma unroll
        for (int mt = 0; mt < 2; mt++)
#pragma unroll
            for (int ks = 0; ks < 2; ks++)
                pa[mt][ks] = *(const bf16x8*)&Ps[w * 32 + mt * 16 + lm][ks * 32 + quad * 8];
#pragma unroll
        for (int mt = 0; mt < 2; mt++)
#pragma unroll
            for (int nt = 0; nt < 4; nt++) {
                f32x4 a = MFMA16(pa[mt][0], vb[nt][0], accO[mt][nt]);
                accO[mt][nt] = MFMA16(pa[mt][1], vb[nt][1], a);
            }
    }

    const int b = bh >> 4, h = bh & 15;
#pragma unroll
    for (int mt = 0; mt < 2; mt++) {
        float inv[4];
#pragma unroll
        for (int r = 0; r < 4; r++) inv[r] = 1.0f / lrow[mt][r];
#pragma unroll
        for (int nt = 0; nt < 4; nt++)
#pragma unroll
            for (int r = 0; r < 4; r++) {
                const int n = n0 + w * 32 + mt * 16 + quad * 4 + r;
                O[((size_t)(b * 2048 + n)) * 1024 + h * 64 + nt * 16 + lm] =
                    (unsigned short)f2b(accO[mt][nt][r] * inv[r]);
            }
    }
}

extern "C" void kernel_launch(void* const* d_in, const int* in_sizes, int n_in,
                              void* d_out, int out_size, void* d_ws, size_t ws_size,
                              hipStream_t stream) {
    const float* x = (const float*)d_in[0];      // [4,2048,1024] fp32
    const float* w_qkv = (const float*)d_in[1];  // [3072,1024] fp32
    const float* w_out = (const float*)d_in[2];  // [1024,1024] fp32
    float* out = (float*)d_out;                  // [4,2048,1024] fp32

    // Workspace: qkv bf16 (Q [bh][n][d], K [bh][n][d], V [bh][d][n]) = 50.3 MB,
    // attn bf16 [B,N,E] = 16.8 MB.
    unsigned short* qkvb = (unsigned short*)d_ws;
    unsigned short* attn = qkvb + 3ull * 8388608;

    // 1) QKV projection (fp32 in, bf16 MFMA) -> Q(scaled)/K row-major, V transposed
    gemm_bt_kernel<2, 1024, true, true>
        <<<dim3(48, 128), 256, 0, stream>>>(x, w_qkv, (void*)qkvb);
    // 2) MFMA flash attention v3 (no-LDS K/V, barrier-free) -> bf16 attn_out
    attn_mfma_kernel<<<dim3(16, 64), 256, 0, stream>>>(qkvb, qkvb + 8388608,
                                                       qkvb + 2 * 8388608, attn);
    // 3) output projection (bf16 A, fp32 W) -> FP32 out
    gemm_bt_kernel<1, 1024, false, true>
        <<<dim3(16, 128), 256, 0, stream>>>((const void*)attn, w_out, out);
}